// Round 5
// baseline (207.851 us; speedup 1.0000x reference)
//
#include <hip/hip_runtime.h>
#include <hip/hip_bf16.h>
#include <hip/hip_fp16.h>
#include <math.h>

// ---------------------------------------------------------------------------
// DisplacementTensors: rad = MLP(radial_encode(|r|)) depends only on |r| ->
// tabulate [interleaved (ra,rv,rd) per channel] (96 f32/row = 384 B, 8192
// entries, 3 MB, L2-resident).  CSR segment-sum WITHOUT global atomics:
//   k_hist / k_colscan / k_scan2 / k_place : CSR build (see below)
//   k_nodes2 : TWO nodes per wave (lane = half x channel), each lane owns all
//              13 outputs of its channel.
// k_nodes2 history:
//   R11 base : 2-wide JIT loop, 48.9 us (VALUBusy 23%, HBM 14% -> latency).
//   R12      : interleaved table row (ONE dwordx3 gather/edge, keep) + NT
//              stores -> 72 us (3x write amplification).  R13: revert NT
//              stores -> 54.7 us (manual rotation movs + NT loads net loss).
//   R14/15   : 8-wide batched loads + predicated 8-wide tail -> 48.0 us,
//              BUT VGPR stayed 36: the scheduler's max-occupancy heuristic
//              re-serialized the batch (8 in-flight float4 needs ~90 VGPR).
//   R16 (this): __launch_bounds__(256, 4) -> min 4 waves/EU, VGPR budget
//              128.  Scheduler now allowed to keep the 8-deep load pipeline
//              live: one vmcnt phase per 8 edges instead of ~700 cyc of
//              serialized latency per edge.  Source otherwise identical.
// Payload: float4 (rs0,rs1,rs2, table BYTE offset) when ws allows, else
// packed uint2 (f16 rs | u16 idx).  dtype (bf16/f32) runtime-detected.
// ---------------------------------------------------------------------------

#define TSIZE 8192
#define DMAX  2.0f           // RBF centers <=1, width 1/8 -> F const beyond ~2
#define EPB   4              // entries per block in k_table
#define HB    128            // edge chunks
#define TILE  10240          // node-tile size (40 KB LDS)
#define NPB   4              // waves per block in k_nodes2 (8 nodes/block)

// f32 concat-weight offsets (floats)
#define O_WRAD 0
#define O_BRAD 256
#define O_WDIR 288
#define O_W1   1312
#define O_B1   3360
#define O_W2   3424
#define O_B2   7520
#define O_W3   7584
#define O_B3   9632
#define O_WV   9664
#define O_WD   10688
#define W_TOT  11712

typedef float        f32x4 __attribute__((ext_vector_type(4)));
typedef unsigned int u32x2 __attribute__((ext_vector_type(2)));

struct TE { float r, v, d; };   // one interleaved table triple (12 B)

__device__ __forceinline__ float lrelu(float x) { return x > 0.0f ? x : 0.1f * x; }

__device__ __forceinline__ float ldf(const void* p, int i, bool f32) {
    return f32 ? ((const float*)p)[i]
               : __uint_as_float(((unsigned int)((const unsigned short*)p)[i]) << 16);
}
__device__ __forceinline__ void stf(void* p, size_t i, float v, bool f32) {
    if (f32) ((float*)p)[i] = v;
    else     ((__hip_bfloat16*)p)[i] = __float2bfloat16(v);
}

__device__ __forceinline__ bool detect_f32(const void* r) {
    const unsigned short* p = (const unsigned short*)r;
    int bad = 0;
#pragma unroll 8
    for (int i = 0; i < 128; i++) {
        float v = __uint_as_float(((unsigned int)p[i]) << 16);
        bad |= (!isfinite(v) || fabsf(v) > 1e5f) ? 1 : 0;
    }
    return bad != 0;
}

// --- prep: flag store | weight->f32 concat | (fallback) zero counts --------
__global__ void k_prep(const void* __restrict__ r_ij,
                       const void* w_rad, const void* b_rad, const void* w_direct,
                       const void* w1, const void* b1, const void* w2, const void* b2,
                       const void* w3, const void* b3, const void* w_v, const void* w_d,
                       float* __restrict__ wcat, int* __restrict__ flag,
                       int* __restrict__ counts, int N) {
    const int b = blockIdx.x;
    if (b == 0) {
        if (threadIdx.x == 0) flag[0] = detect_f32(r_ij) ? 1 : 0;
    } else if (b <= 11) {
        const bool f32 = detect_f32(r_ij);
        const void* src; int cnt; int off;
        switch (b) {
            case 1:  src = w_rad;    cnt = 256;  off = O_WRAD; break;
            case 2:  src = b_rad;    cnt = 32;   off = O_BRAD; break;
            case 3:  src = w_direct; cnt = 1024; off = O_WDIR; break;
            case 4:  src = w1;       cnt = 2048; off = O_W1;   break;
            case 5:  src = b1;       cnt = 64;   off = O_B1;   break;
            case 6:  src = w2;       cnt = 4096; off = O_W2;   break;
            case 7:  src = b2;       cnt = 64;   off = O_B2;   break;
            case 8:  src = w3;       cnt = 2048; off = O_W3;   break;
            case 9:  src = b3;       cnt = 32;   off = O_B3;   break;
            case 10: src = w_v;      cnt = 1024; off = O_WV;   break;
            default: src = w_d;      cnt = 1024; off = O_WD;   break;
        }
        for (int i = threadIdx.x; i < cnt; i += blockDim.x)
            wcat[off + i] = ldf(src, i, f32);
    } else if (counts) {
        int i = (b - 12) * blockDim.x + threadIdx.x;
        if (i < N) counts[i] = 0;
    }
}

// --- LUT build: 4 entries/block, wave = entry, lane = neuron ---------------
// table row e: 32 x (ra, rv, rd) interleaved triples -> lane a gathers ONE
// contiguous 12-B read at e*384 + a*12 in k_nodes2.
__global__ void __launch_bounds__(64 * EPB) k_table(const float* __restrict__ wcat,
                                                    float* __restrict__ tabI) {
    __shared__ float Lh[EPB][32], Lt1[EPB][64], Lt2[EPB][64], Lrad[EPB][32];

    const int s = threadIdx.x >> 6;
    const int j = threadIdx.x & 63;
    const int e = blockIdx.x * EPB + s;
    const float d = (float)e * (DMAX / (float)(TSIZE - 1));

    float enc[8];
#pragma unroll
    for (int k = 0; k < 8; k++) {
        float t = (d - (float)k * (1.0f / 7.0f)) * 8.0f;
        enc[k] = expf(-t * t);
    }

    if (j < 32) {
        float hv = wcat[O_BRAD + j];
#pragma unroll
        for (int k = 0; k < 8; k++) hv = fmaf(enc[k], wcat[O_WRAD + k * 32 + j], hv);
        Lh[s][j] = hv;
    }
    __syncthreads();

    {
        float v = wcat[O_B1 + j];
#pragma unroll
        for (int i = 0; i < 32; i++) v = fmaf(Lh[s][i], wcat[O_W1 + i * 64 + j], v);
        Lt1[s][j] = lrelu(v);
    }
    __syncthreads();

    {
        float v = wcat[O_B2 + j];
#pragma unroll
        for (int i = 0; i < 64; i++) v = fmaf(Lt1[s][i], wcat[O_W2 + i * 64 + j], v);
        Lt2[s][j] = lrelu(v);
    }
    __syncthreads();

    if (j < 32) {
        float v = wcat[O_B3 + j];
#pragma unroll
        for (int i = 0; i < 64; i++) v = fmaf(Lt2[s][i], wcat[O_W3 + i * 32 + j], v);
#pragma unroll
        for (int i = 0; i < 32; i++) v = fmaf(Lh[s][i], wcat[O_WDIR + i * 32 + j], v);
        Lrad[s][j] = v;
    }
    __syncthreads();

    if (j < 32) {
        float sv = 0.0f, sd = 0.0f;
#pragma unroll
        for (int i = 0; i < 32; i++) {
            float ri = Lrad[s][i];
            sv = fmaf(ri, wcat[O_WV + i * 32 + j], sv);
            sd = fmaf(ri, wcat[O_WD + i * 32 + j], sd);
        }
        float* row = tabI + (size_t)e * 96 + j * 3;
        row[0] = Lrad[s][j];
        row[1] = sv;
        row[2] = sd;
    }
}

// --- CSR pass 1: per-(chunk,tile) LDS histogram -> u16 cnt -----------------
__global__ void __launch_bounds__(256) k_hist(const int* __restrict__ src, int E,
                                              int chunk,
                                              unsigned short* __restrict__ cnt,
                                              int N) {
    __shared__ int lcnt[TILE];
    const int b = blockIdx.x % HB;
    const int t = blockIdx.x / HB;
    const int lo = b * chunk;
    const int hi = min(lo + chunk, E);
    const int t0 = t * TILE;
    const int tl = min(TILE, N - t0);

    for (int i = threadIdx.x; i < tl; i += 256) lcnt[i] = 0;
    __syncthreads();
    for (int e = lo + threadIdx.x; e < hi; e += 256) {
        const int s = src[e] - t0;
        if ((unsigned)s < (unsigned)tl) atomicAdd(&lcnt[s], 1);
    }
    __syncthreads();
    unsigned short* out = cnt + (size_t)(t * HB + b) * TILE;
    for (int i = threadIdx.x; i < tl; i += 256)
        out[i] = (unsigned short)lcnt[i];
}

// --- CSR pass 2: per-node prefix over chunks; coarse sum per 64-node block -
__global__ void __launch_bounds__(64) k_colscan(unsigned short* __restrict__ cnt,
                                                int* __restrict__ tot,
                                                int* __restrict__ coarse, int N) {
    const int lane = threadIdx.x;
    const int n = blockIdx.x * 64 + lane;
    int run = 0;
    if (n < N) {
        const int t = n / TILE;
        const int nl = n % TILE;
        unsigned short* col = cnt + (size_t)(t * HB) * TILE + nl;
#pragma unroll 4
        for (int b = 0; b < HB; b++) {
            int c = col[(size_t)b * TILE];
            col[(size_t)b * TILE] = (unsigned short)run;
            run += c;
        }
        tot[n] = run;
    }
    int s = run;
    for (int off = 32; off > 0; off >>= 1) s += __shfl_down(s, off);
    if (lane == 0) coarse[blockIdx.x] = s;
}

// --- CSR pass 3: rowstart; coarse prefix summed cooperatively --------------
__global__ void __launch_bounds__(64) k_scan2(const int* __restrict__ tot,
                                              const int* __restrict__ coarse,
                                              int* __restrict__ rowstart, int N) {
    const int lane = threadIdx.x;
    const int b = blockIdx.x;
    int cp = 0;
    for (int j = lane; j < b; j += 64) cp += coarse[j];
    for (int off = 32; off > 0; off >>= 1) cp += __shfl_down(cp, off);
    const int cpre = __shfl(cp, 0);

    const int n = b * 64 + lane;
    const int v = (n < N) ? tot[n] : 0;
    int inc = v;
    for (int off = 1; off < 64; off <<= 1) {
        int y = __shfl_up(inc, off);
        if (lane >= off) inc += y;
    }
    if (n < N) rowstart[n] = cpre + inc - v;
    if (n == N - 1) rowstart[N] = cpre + inc;
}

// --- CSR pass 4: place payload via LDS cursor ------------------------------
template <bool P16>
__global__ void __launch_bounds__(256) k_place(
        const int* __restrict__ src, int E, int chunk,
        const unsigned short* __restrict__ cnt, const int* __restrict__ rowstart,
        const void* __restrict__ r_ij, const int* __restrict__ flag,
        void* __restrict__ epsv, int N) {
    __shared__ int cur[TILE];
    const int b = blockIdx.x % HB;
    const int t = blockIdx.x / HB;
    const int lo = b * chunk;
    const int hi = min(lo + chunk, E);
    const int t0 = t * TILE;
    const int tl = min(TILE, N - t0);
    const bool f32 = flag[0] != 0;

    const unsigned short* base = cnt + (size_t)(t * HB + b) * TILE;
    for (int i = threadIdx.x; i < tl; i += 256)
        cur[i] = rowstart[t0 + i] + (int)base[i];
    __syncthreads();
    for (int e = lo + threadIdx.x; e < hi; e += 256) {
        const int s = src[e] - t0;
        if ((unsigned)s < (unsigned)tl) {
            const int pos = atomicAdd(&cur[s], 1);
            const float x = ldf(r_ij, 3 * e + 0, f32);
            const float y = ldf(r_ij, 3 * e + 1, f32);
            const float z = ldf(r_ij, 3 * e + 2, f32);
            const float d2 = x * x + y * y + z * z;
            const float inv = rsqrtf(1.0f + 49.0f * d2);  // tens_sigmoid(7r)
            const float u = fminf(sqrtf(d2), DMAX) * ((float)(TSIZE - 1) / DMAX);
            const int ti = (int)(u + 0.5f);               // nearest, <= TSIZE-1
            const float rs0 = 7.0f * x * inv, rs1 = 7.0f * y * inv,
                        rs2 = 7.0f * z * inv;
            if (P16) {
                ((float4*)epsv)[pos] =
                    make_float4(rs0, rs1, rs2, __int_as_float(ti * 384));
            } else {
                const unsigned int h0 = __half_as_ushort(__float2half(rs0));
                const unsigned int h1 = __half_as_ushort(__float2half(rs1));
                const unsigned int h2 = __half_as_ushort(__float2half(rs2));
                ((uint2*)epsv)[pos] =
                    make_uint2(h0 | (h1 << 16), h2 | ((unsigned)ti << 16));
            }
        }
    }
}

// --- per-node accumulation: TWO nodes per wave, 8-wide batched loads -------
// lane = (half = lane>>5, channel a = lane&31); each lane owns all 13 outputs
// of channel a of node n0+half.  Per step: 8 independent payload loads, then
// 8 independent table gathers (ONE dwordx3 each, interleaved rows), then
// 8 x 22 VALU accumulate -- one vmcnt wait amortizes over 8 edges.
// __launch_bounds__(256, 4): min 4 waves/EU -> 128-VGPR budget, so the
// scheduler keeps the 8-deep load pipeline in registers (R15: without it,
// the max-occupancy heuristic re-serialized everything at VGPR=36).
// Remainder handled by the SAME 8-wide shape, predicated: index clamped to
// [0, mylen-1], contribution zero-masked.
template <bool P16>
__global__ void __launch_bounds__(64 * NPB, 4) k_nodes2(
    const void* __restrict__ epsv,
    const int* __restrict__ rowstart,
    const float* __restrict__ tabI,
    const int* __restrict__ flag,
    void* __restrict__ out, int N) {
    const int wave = threadIdx.x >> 6;
    const int lane = threadIdx.x & 63;
    const int n0 = (blockIdx.x * NPB + wave) * 2;
    const int a = lane & 31;
    const int half = lane >> 5;
    const int myn = n0 + half;
    const bool f32 = flag[0] != 0;
    const char* tabA = (const char*)tabI + a * 12;   // interleaved triple base

    int s0 = 0, s1 = 0;
    if (myn < N) { s0 = rowstart[myn]; s1 = rowstart[myn + 1]; }
    const int mylen = s1 - s0;
    const int lenA = __shfl(mylen, 0);
    const int lenB = __shfl(mylen, 32);
    const int minl = min(lenA, lenB);
    const int maxl = max(lenA, lenB);
    const int mclamp = max(mylen - 1, 0);

    float accA = 0.f, v0 = 0.f, v1 = 0.f, v2 = 0.f;
    float d00 = 0.f, d01 = 0.f, d02 = 0.f,
          d10 = 0.f, d11 = 0.f, d12 = 0.f,
          d20 = 0.f, d21 = 0.f, d22 = 0.f;

#define LDQ(QF, QH, IDX)                                                      \
    do {                                                                      \
        if (P16) QF = *((const f32x4*)epsv + (IDX));                          \
        else     QH = *((const u32x2*)epsv + (IDX));                          \
    } while (0)

#define TOFF(QF, QH) (P16 ? __float_as_int(QF.w) : (int)(QH.y >> 16) * 384)

#define LDT(T, QF, QH)                                                        \
    do { T = *(const TE*)(tabA + TOFF(QF, QH)); } while (0)

#define DECODE(QF, QH, X, Y, Z)                                               \
    do {                                                                      \
        if (P16) { X = QF.x; Y = QF.y; Z = QF.z; }                            \
        else {                                                                \
            X = __half2float(__ushort_as_half((unsigned short)(QH.x & 0xffffu))); \
            Y = __half2float(__ushort_as_half((unsigned short)(QH.x >> 16)));     \
            Z = __half2float(__ushort_as_half((unsigned short)(QH.y & 0xffffu))); \
        }                                                                     \
    } while (0)

#define ACCT(T, X, Y, Z)                                                      \
    do {                                                                      \
        accA += (T).r;                                                        \
        v0 += (T).v * (X); v1 += (T).v * (Y); v2 += (T).v * (Z);              \
        const float _tx = (T).d * (X), _ty = (T).d * (Y), _tz = (T).d * (Z);  \
        d00 += _tx * (X); d01 += _tx * (Y); d02 += _tx * (Z);                 \
        d10 += _ty * (X); d11 += _ty * (Y); d12 += _ty * (Z);                 \
        d20 += _tz * (X); d21 += _tz * (Y); d22 += _tz * (Z);                 \
    } while (0)

    f32x4 qf0, qf1, qf2, qf3, qf4, qf5, qf6, qf7;
    u32x2 qh0, qh1, qh2, qh3, qh4, qh5, qh6, qh7;
    TE te0, te1, te2, te3, te4, te5, te6, te7;

    int i = 0;
    // ---- main: unpredicated 8-wide batches up to minl ----
    for (; i + 8 <= minl; i += 8) {
#define SL(K) LDQ(qf##K, qh##K, s0 + i + K)
        SL(0); SL(1); SL(2); SL(3); SL(4); SL(5); SL(6); SL(7);
#undef SL
#define ST(K) LDT(te##K, qf##K, qh##K)
        ST(0); ST(1); ST(2); ST(3); ST(4); ST(5); ST(6); ST(7);
#undef ST
#define SA(K)                                                                 \
        do { float x, y, z; DECODE(qf##K, qh##K, x, y, z);                    \
             ACCT(te##K, x, y, z); } while (0)
        SA(0); SA(1); SA(2); SA(3); SA(4); SA(5); SA(6); SA(7);
#undef SA
    }
    // ---- remainder: predicated 8-wide batches up to maxl ----
    for (; i < maxl; i += 8) {
        float m0, m1, m2, m3, m4, m5, m6, m7;
#define SLP(K)                                                                \
        do { const int j = i + K;                                             \
             const int jc = j < mylen ? j : mclamp;                           \
             m##K = (j < mylen) ? 1.0f : 0.0f;                                \
             LDQ(qf##K, qh##K, s0 + jc); } while (0)
        SLP(0); SLP(1); SLP(2); SLP(3); SLP(4); SLP(5); SLP(6); SLP(7);
#undef SLP
#define ST(K) LDT(te##K, qf##K, qh##K)
        ST(0); ST(1); ST(2); ST(3); ST(4); ST(5); ST(6); ST(7);
#undef ST
#define SAP(K)                                                                \
        do { float x, y, z; DECODE(qf##K, qh##K, x, y, z);                    \
             te##K.r *= m##K; te##K.v *= m##K; te##K.d *= m##K;               \
             ACCT(te##K, x, y, z); } while (0)
        SAP(0); SAP(1); SAP(2); SAP(3); SAP(4); SAP(5); SAP(6); SAP(7);
#undef SAP
    }
#undef LDQ
#undef TOFF
#undef LDT
#undef DECODE
#undef ACCT

    if (myn >= N) return;
    const size_t baseV = (size_t)N * 32;
    const size_t baseD = (size_t)N * 128;
    stf(out, (size_t)myn * 32 + a, accA, f32);
    const size_t vb = baseV + (size_t)myn * 96 + a * 3;
    stf(out, vb + 0, v0, f32);
    stf(out, vb + 1, v1, f32);
    stf(out, vb + 2, v2, f32);
    const size_t db = baseD + (size_t)myn * 288 + a * 9;
    stf(out, db + 0, d00, f32);
    stf(out, db + 1, d01, f32);
    stf(out, db + 2, d02, f32);
    stf(out, db + 3, d10, f32);
    stf(out, db + 4, d11, f32);
    stf(out, db + 5, d12, f32);
    stf(out, db + 6, d20, f32);
    stf(out, db + 7, d21, f32);
    stf(out, db + 8, d22, f32);
}

// --- fallback CSR (global atomics) + perm-based nodes ----------------------
__global__ void k_rank_g(const int* __restrict__ src, int* __restrict__ counts,
                         int* __restrict__ rank, int E) {
    int e = blockIdx.x * blockDim.x + threadIdx.x;
    if (e < E) rank[e] = atomicAdd(&counts[src[e]], 1);
}
__global__ void k_scan_g(const int* __restrict__ counts, int* __restrict__ rowstart,
                         int N, int E) {
    __shared__ int part[1024];
    const int t = threadIdx.x;
    const int CH = (N + 1023) / 1024;
    const int lo = t * CH;
    const int hi = min(lo + CH, N);
    int s = 0;
    for (int i = lo; i < hi; i++) s += counts[i];
    part[t] = s;
    __syncthreads();
    for (int off = 1; off < 1024; off <<= 1) {
        int v = part[t];
        int w = (t >= off) ? part[t - off] : 0;
        __syncthreads();
        part[t] = v + w;
        __syncthreads();
    }
    int run = (t == 0) ? 0 : part[t - 1];
    for (int i = lo; i < hi; i++) { rowstart[i] = run; run += counts[i]; }
    if (t == 0) rowstart[N] = E;
}
__global__ void k_place_g(const int* __restrict__ src, const int* __restrict__ rank,
                          const int* __restrict__ rowstart,
                          int* __restrict__ perm, int E) {
    int e = blockIdx.x * blockDim.x + threadIdx.x;
    if (e < E) perm[rowstart[src[e]] + rank[e]] = e;
}
__global__ void __launch_bounds__(256) k_nodes_fb(
    const int* __restrict__ perm, const void* __restrict__ r_ij,
    const int* __restrict__ rowstart, const float* __restrict__ tabI,
    const int* __restrict__ flag, void* __restrict__ out, int N) {
    const int wave = threadIdx.x >> 6;
    const int lane = threadIdx.x & 63;
    const int n = blockIdx.x * 4 + wave;
    if (n >= N) return;
    const int a = lane & 31;
    const bool hi = (lane >> 5) != 0;
    const bool f32 = flag[0] != 0;
    const int s0 = rowstart[n], s1 = rowstart[n + 1];
    float accR = 0.f, acc1 = 0.f, acc2 = 0.f, acc3 = 0.f,
          acc4 = 0.f, acc5 = 0.f, acc6 = 0.f;
    for (int idx = s0; idx < s1; idx++) {
        const int e = perm[idx];
        const float x0 = ldf(r_ij, 3 * e + 0, f32);
        const float y0 = ldf(r_ij, 3 * e + 1, f32);
        const float z0 = ldf(r_ij, 3 * e + 2, f32);
        const float d2 = x0 * x0 + y0 * y0 + z0 * z0;
        const float inv = rsqrtf(1.0f + 49.0f * d2);
        const float x = 7.0f * x0 * inv, y = 7.0f * y0 * inv, z = 7.0f * z0 * inv;
        const float u = fminf(sqrtf(d2), DMAX) * ((float)(TSIZE - 1) / DMAX);
        const int b = (int)(u + 0.5f) * 96 + a * 3;   // interleaved row
        const float ra = tabI[b], rv = tabI[b + 1], rd = tabI[b + 2];
        const float b1 = (hi ? rd : rv) * (hi ? y : 1.0f);
        const float b2 = rd * (hi ? z : x);
        accR += ra;
        acc1 += b1 * x; acc2 += b1 * y; acc3 += b1 * z;
        acc4 += b2 * x; acc5 += b2 * y; acc6 += b2 * z;
    }
    const size_t baseV = (size_t)N * 32;
    const size_t baseD = (size_t)N * 128;
    if (!hi) {
        stf(out, (size_t)n * 32 + a, accR, f32);
        const size_t vb = baseV + (size_t)n * 96 + a * 3;
        stf(out, vb + 0, acc1, f32);
        stf(out, vb + 1, acc2, f32);
        stf(out, vb + 2, acc3, f32);
        const size_t db = baseD + (size_t)n * 288 + a * 9;
        stf(out, db + 0, acc4, f32);
        stf(out, db + 1, acc5, f32);
        stf(out, db + 2, acc6, f32);
    } else {
        const size_t db = baseD + (size_t)n * 288 + a * 9;
        stf(out, db + 3, acc1, f32);
        stf(out, db + 4, acc2, f32);
        stf(out, db + 5, acc3, f32);
        stf(out, db + 6, acc4, f32);
        stf(out, db + 7, acc5, f32);
        stf(out, db + 8, acc6, f32);
    }
}

extern "C" void kernel_launch(void* const* d_in, const int* in_sizes, int n_in,
                              void* d_out, int out_size, void* d_ws, size_t ws_size,
                              hipStream_t stream) {
    const void* r_ij     = d_in[0];
    const void* w_rad    = d_in[1];
    const void* b_rad    = d_in[2];
    const void* w_direct = d_in[3];
    const void* w1       = d_in[4];
    const void* b1       = d_in[5];
    const void* w2       = d_in[6];
    const void* b2       = d_in[7];
    const void* w3       = d_in[8];
    const void* b3       = d_in[9];
    const void* w_v      = d_in[10];
    const void* w_d      = d_in[11];
    const int* edges_src = (const int*)d_in[12];

    const int E = in_sizes[12];
    const int N = out_size / 416;   // 32 + 96 + 288 per node
    const int chunk = (E + HB - 1) / HB;
    const int ntiles = (N + TILE - 1) / TILE;
    const int NB = (N + 63) / 64;

    const size_t cntBytes  = (size_t)ntiles * HB * TILE * 2;
    const size_t tailBytes = ((size_t)W_TOT + 4) * 4 + (size_t)TSIZE * 96 * 4
                           + cntBytes + ((size_t)N + NB + N + 1) * 4;
    const bool p16 = ws_size >= (size_t)E * 16 + tailBytes + 64;
    const bool p8  = !p16 && ws_size >= (size_t)E * 8 + tailBytes + 64;

    char* w = (char*)d_ws;
    if (p16 || p8) {
        const size_t slot = (size_t)E * (p16 ? 16 : 8);
        void* eps     = (void*)w;
        float* wcat   = (float*)(w + slot);
        int* flag     = (int*)(wcat + W_TOT);
        float* tabI   = (float*)(flag + 4);
        unsigned short* cnt = (unsigned short*)(tabI + (size_t)TSIZE * 96);
        int* tot      = (int*)((char*)cnt + cntBytes);
        int* coarse   = tot + N;              // NB entries
        int* rowstart = coarse + NB;          // N+1

        const int nodeBlocks = (N + 2 * NPB - 1) / (2 * NPB);
        k_prep<<<12, 256, 0, stream>>>(
            r_ij, w_rad, b_rad, w_direct, w1, b1, w2, b2, w3, b3, w_v, w_d,
            wcat, flag, nullptr, N);
        k_table<<<TSIZE / EPB, 64 * EPB, 0, stream>>>(wcat, tabI);
        k_hist<<<HB * ntiles, 256, 0, stream>>>(edges_src, E, chunk, cnt, N);
        k_colscan<<<NB, 64, 0, stream>>>(cnt, tot, coarse, N);
        k_scan2<<<NB, 64, 0, stream>>>(tot, coarse, rowstart, N);
        if (p16) {
            k_place<true><<<HB * ntiles, 256, 0, stream>>>(
                edges_src, E, chunk, cnt, rowstart, r_ij, flag, eps, N);
            k_nodes2<true><<<nodeBlocks, 64 * NPB, 0, stream>>>(
                eps, rowstart, tabI, flag, d_out, N);
        } else {
            k_place<false><<<HB * ntiles, 256, 0, stream>>>(
                edges_src, E, chunk, cnt, rowstart, r_ij, flag, eps, N);
            k_nodes2<false><<<nodeBlocks, 64 * NPB, 0, stream>>>(
                eps, rowstart, tabI, flag, d_out, N);
        }
    } else {
        // fallback: global-atomic rank path, perm-indexed nodes
        int* perm     = (int*)w;              // E
        float* wcat   = (float*)(w + (size_t)E * 4);
        int* flag     = (int*)(wcat + W_TOT);
        float* tabI   = (float*)(flag + 4);
        int* counts   = (int*)(tabI + (size_t)TSIZE * 96);
        int* rowstart = counts + N;           // N+1
        int* rank     = rowstart + N + 1;     // E

        k_prep<<<12 + (N + 255) / 256, 256, 0, stream>>>(
            r_ij, w_rad, b_rad, w_direct, w1, b1, w2, b2, w3, b3, w_v, w_d,
            wcat, flag, counts, N);
        k_table<<<TSIZE / EPB, 64 * EPB, 0, stream>>>(wcat, tabI);
        k_rank_g<<<(E + 255) / 256, 256, 0, stream>>>(edges_src, counts, rank, E);
        k_scan_g<<<1, 1024, 0, stream>>>(counts, rowstart, N, E);
        k_place_g<<<(E + 255) / 256, 256, 0, stream>>>(edges_src, rank, rowstart,
                                                       perm, E);
        k_nodes_fb<<<(N + 3) / 4, 256, 0, stream>>>(
            perm, r_ij, rowstart, tabI, flag, d_out, N);
    }
}

// Round 7
// 200.966 us; speedup vs baseline: 1.0343x; 1.0343x over previous
//
#include <hip/hip_runtime.h>
#include <hip/hip_bf16.h>
#include <hip/hip_fp16.h>
#include <math.h>

// ---------------------------------------------------------------------------
// DisplacementTensors: rad = MLP(radial_encode(|r|)) depends only on |r| ->
// tabulate per-channel (ra,rv,rd,pad) 16-B quads (128 f32/row = 512 B,
// 8192 entries, 4 MB, L2/L3-resident).  CSR segment-sum WITHOUT atomics:
//   k_hist / k_colscan / k_scan2 / k_place : CSR build
//   k_nodes2 : TWO nodes per wave (lane = half x channel), each lane owns all
//              13 outputs of its channel.
// k_nodes2 history:
//   R11 base : 2-wide JIT loop, 48.9 us (VALUBusy 23%, HBM 14% -> latency).
//   R12/13   : NT stores = 3x write amplification (revert).
//   R14/15   : 8-wide source-level batch -> VGPR stayed 36, scheduler
//              re-serialized (sinks loads to uses to minimize pressure).
//   R16      : __launch_bounds__(256,4) -> VGPR STILL 36: min-waves only
//              CAPS registers, scheduler still minimizes pressure.
//   R17      : inline-asm load blocks the scheduler cannot split:
//              8x global_load_dwordx4 (payload) + vmcnt(0), then
//              8x global_load_dwordx4 (table) + vmcnt(0).  Outputs are asm
//              operands -> 8 results simultaneously live -> ~2 latency
//              events per 8 edges.  Table quad padded 12->16 B (aligned).
//              (R17 run lost to infra failure; resubmitted unchanged.)
// Payload: float4 (rs0,rs1,rs2, table BYTE offset) when ws allows, else
// packed uint2 (f16 rs | u16 idx).  dtype (bf16/f32) runtime-detected.
// ---------------------------------------------------------------------------

#define TSIZE 8192
#define DMAX  2.0f           // RBF centers <=1, width 1/8 -> F const beyond ~2
#define EPB   4              // entries per block in k_table
#define HB    128            // edge chunks
#define TILE  10240          // node-tile size (40 KB LDS)
#define NPB   4              // waves per block in k_nodes2 (8 nodes/block)
#define ROWB  512            // table row bytes (32 ch x 16 B)
#define ROWF  128            // table row floats

// f32 concat-weight offsets (floats)
#define O_WRAD 0
#define O_BRAD 256
#define O_WDIR 288
#define O_W1   1312
#define O_B1   3360
#define O_W2   3424
#define O_B2   7520
#define O_W3   7584
#define O_B3   9632
#define O_WV   9664
#define O_WD   10688
#define W_TOT  11712

typedef float        f32x4 __attribute__((ext_vector_type(4)));
typedef unsigned int u32x2 __attribute__((ext_vector_type(2)));

struct TE { float r, v, d; };   // table triple view (12 of the 16 B)

__device__ __forceinline__ float lrelu(float x) { return x > 0.0f ? x : 0.1f * x; }

__device__ __forceinline__ float ldf(const void* p, int i, bool f32) {
    return f32 ? ((const float*)p)[i]
               : __uint_as_float(((unsigned int)((const unsigned short*)p)[i]) << 16);
}
__device__ __forceinline__ void stf(void* p, size_t i, float v, bool f32) {
    if (f32) ((float*)p)[i] = v;
    else     ((__hip_bfloat16*)p)[i] = __float2bfloat16(v);
}

__device__ __forceinline__ bool detect_f32(const void* r) {
    const unsigned short* p = (const unsigned short*)r;
    int bad = 0;
#pragma unroll 8
    for (int i = 0; i < 128; i++) {
        float v = __uint_as_float(((unsigned int)p[i]) << 16);
        bad |= (!isfinite(v) || fabsf(v) > 1e5f) ? 1 : 0;
    }
    return bad != 0;
}

// 8 independent 16-B loads in ONE asm block: scheduler cannot split it, so
// all 8 results are simultaneously live (forces the 8-deep pipeline R14-R16
// could not get from the compiler).  Internal vmcnt(0) + data-dependence on
// the outputs orders all consumers after the loads complete.
__device__ __forceinline__ void load8x16(
    const void* p0, const void* p1, const void* p2, const void* p3,
    const void* p4, const void* p5, const void* p6, const void* p7,
    f32x4& q0, f32x4& q1, f32x4& q2, f32x4& q3,
    f32x4& q4, f32x4& q5, f32x4& q6, f32x4& q7) {
    asm volatile(
        "global_load_dwordx4 %0, %8, off\n\t"
        "global_load_dwordx4 %1, %9, off\n\t"
        "global_load_dwordx4 %2, %10, off\n\t"
        "global_load_dwordx4 %3, %11, off\n\t"
        "global_load_dwordx4 %4, %12, off\n\t"
        "global_load_dwordx4 %5, %13, off\n\t"
        "global_load_dwordx4 %6, %14, off\n\t"
        "global_load_dwordx4 %7, %15, off\n\t"
        "s_waitcnt vmcnt(0)"
        : "=&v"(q0), "=&v"(q1), "=&v"(q2), "=&v"(q3),
          "=&v"(q4), "=&v"(q5), "=&v"(q6), "=&v"(q7)
        : "v"(p0), "v"(p1), "v"(p2), "v"(p3),
          "v"(p4), "v"(p5), "v"(p6), "v"(p7));
}

// --- prep: flag store | weight->f32 concat | (fallback) zero counts --------
__global__ void k_prep(const void* __restrict__ r_ij,
                       const void* w_rad, const void* b_rad, const void* w_direct,
                       const void* w1, const void* b1, const void* w2, const void* b2,
                       const void* w3, const void* b3, const void* w_v, const void* w_d,
                       float* __restrict__ wcat, int* __restrict__ flag,
                       int* __restrict__ counts, int N) {
    const int b = blockIdx.x;
    if (b == 0) {
        if (threadIdx.x == 0) flag[0] = detect_f32(r_ij) ? 1 : 0;
    } else if (b <= 11) {
        const bool f32 = detect_f32(r_ij);
        const void* src; int cnt; int off;
        switch (b) {
            case 1:  src = w_rad;    cnt = 256;  off = O_WRAD; break;
            case 2:  src = b_rad;    cnt = 32;   off = O_BRAD; break;
            case 3:  src = w_direct; cnt = 1024; off = O_WDIR; break;
            case 4:  src = w1;       cnt = 2048; off = O_W1;   break;
            case 5:  src = b1;       cnt = 64;   off = O_B1;   break;
            case 6:  src = w2;       cnt = 4096; off = O_W2;   break;
            case 7:  src = b2;       cnt = 64;   off = O_B2;   break;
            case 8:  src = w3;       cnt = 2048; off = O_W3;   break;
            case 9:  src = b3;       cnt = 32;   off = O_B3;   break;
            case 10: src = w_v;      cnt = 1024; off = O_WV;   break;
            default: src = w_d;      cnt = 1024; off = O_WD;   break;
        }
        for (int i = threadIdx.x; i < cnt; i += blockDim.x)
            wcat[off + i] = ldf(src, i, f32);
    } else if (counts) {
        int i = (b - 12) * blockDim.x + threadIdx.x;
        if (i < N) counts[i] = 0;
    }
}

// --- LUT build: 4 entries/block, wave = entry, lane = neuron ---------------
// table row e: 32 x (ra, rv, rd, pad) 16-B quads -> lane a gathers ONE
// aligned dwordx4 at e*512 + a*16 in k_nodes2.
__global__ void __launch_bounds__(64 * EPB) k_table(const float* __restrict__ wcat,
                                                    float* __restrict__ tabI) {
    __shared__ float Lh[EPB][32], Lt1[EPB][64], Lt2[EPB][64], Lrad[EPB][32];

    const int s = threadIdx.x >> 6;
    const int j = threadIdx.x & 63;
    const int e = blockIdx.x * EPB + s;
    const float d = (float)e * (DMAX / (float)(TSIZE - 1));

    float enc[8];
#pragma unroll
    for (int k = 0; k < 8; k++) {
        float t = (d - (float)k * (1.0f / 7.0f)) * 8.0f;
        enc[k] = expf(-t * t);
    }

    if (j < 32) {
        float hv = wcat[O_BRAD + j];
#pragma unroll
        for (int k = 0; k < 8; k++) hv = fmaf(enc[k], wcat[O_WRAD + k * 32 + j], hv);
        Lh[s][j] = hv;
    }
    __syncthreads();

    {
        float v = wcat[O_B1 + j];
#pragma unroll
        for (int i = 0; i < 32; i++) v = fmaf(Lh[s][i], wcat[O_W1 + i * 64 + j], v);
        Lt1[s][j] = lrelu(v);
    }
    __syncthreads();

    {
        float v = wcat[O_B2 + j];
#pragma unroll
        for (int i = 0; i < 64; i++) v = fmaf(Lt1[s][i], wcat[O_W2 + i * 64 + j], v);
        Lt2[s][j] = lrelu(v);
    }
    __syncthreads();

    if (j < 32) {
        float v = wcat[O_B3 + j];
#pragma unroll
        for (int i = 0; i < 64; i++) v = fmaf(Lt2[s][i], wcat[O_W3 + i * 32 + j], v);
#pragma unroll
        for (int i = 0; i < 32; i++) v = fmaf(Lh[s][i], wcat[O_WDIR + i * 32 + j], v);
        Lrad[s][j] = v;
    }
    __syncthreads();

    if (j < 32) {
        float sv = 0.0f, sd = 0.0f;
#pragma unroll
        for (int i = 0; i < 32; i++) {
            float ri = Lrad[s][i];
            sv = fmaf(ri, wcat[O_WV + i * 32 + j], sv);
            sd = fmaf(ri, wcat[O_WD + i * 32 + j], sd);
        }
        float* row = tabI + (size_t)e * ROWF + j * 4;
        row[0] = Lrad[s][j];
        row[1] = sv;
        row[2] = sd;
        row[3] = 0.0f;
    }
}

// --- CSR pass 1: per-(chunk,tile) LDS histogram -> u16 cnt -----------------
__global__ void __launch_bounds__(256) k_hist(const int* __restrict__ src, int E,
                                              int chunk,
                                              unsigned short* __restrict__ cnt,
                                              int N) {
    __shared__ int lcnt[TILE];
    const int b = blockIdx.x % HB;
    const int t = blockIdx.x / HB;
    const int lo = b * chunk;
    const int hi = min(lo + chunk, E);
    const int t0 = t * TILE;
    const int tl = min(TILE, N - t0);

    for (int i = threadIdx.x; i < tl; i += 256) lcnt[i] = 0;
    __syncthreads();
    for (int e = lo + threadIdx.x; e < hi; e += 256) {
        const int s = src[e] - t0;
        if ((unsigned)s < (unsigned)tl) atomicAdd(&lcnt[s], 1);
    }
    __syncthreads();
    unsigned short* out = cnt + (size_t)(t * HB + b) * TILE;
    for (int i = threadIdx.x; i < tl; i += 256)
        out[i] = (unsigned short)lcnt[i];
}

// --- CSR pass 2: per-node prefix over chunks; coarse sum per 64-node block -
__global__ void __launch_bounds__(64) k_colscan(unsigned short* __restrict__ cnt,
                                                int* __restrict__ tot,
                                                int* __restrict__ coarse, int N) {
    const int lane = threadIdx.x;
    const int n = blockIdx.x * 64 + lane;
    int run = 0;
    if (n < N) {
        const int t = n / TILE;
        const int nl = n % TILE;
        unsigned short* col = cnt + (size_t)(t * HB) * TILE + nl;
#pragma unroll 4
        for (int b = 0; b < HB; b++) {
            int c = col[(size_t)b * TILE];
            col[(size_t)b * TILE] = (unsigned short)run;
            run += c;
        }
        tot[n] = run;
    }
    int s = run;
    for (int off = 32; off > 0; off >>= 1) s += __shfl_down(s, off);
    if (lane == 0) coarse[blockIdx.x] = s;
}

// --- CSR pass 3: rowstart; coarse prefix summed cooperatively --------------
__global__ void __launch_bounds__(64) k_scan2(const int* __restrict__ tot,
                                              const int* __restrict__ coarse,
                                              int* __restrict__ rowstart, int N) {
    const int lane = threadIdx.x;
    const int b = blockIdx.x;
    int cp = 0;
    for (int j = lane; j < b; j += 64) cp += coarse[j];
    for (int off = 32; off > 0; off >>= 1) cp += __shfl_down(cp, off);
    const int cpre = __shfl(cp, 0);

    const int n = b * 64 + lane;
    const int v = (n < N) ? tot[n] : 0;
    int inc = v;
    for (int off = 1; off < 64; off <<= 1) {
        int y = __shfl_up(inc, off);
        if (lane >= off) inc += y;
    }
    if (n < N) rowstart[n] = cpre + inc - v;
    if (n == N - 1) rowstart[N] = cpre + inc;
}

// --- CSR pass 4: place payload via LDS cursor ------------------------------
template <bool P16>
__global__ void __launch_bounds__(256) k_place(
        const int* __restrict__ src, int E, int chunk,
        const unsigned short* __restrict__ cnt, const int* __restrict__ rowstart,
        const void* __restrict__ r_ij, const int* __restrict__ flag,
        void* __restrict__ epsv, int N) {
    __shared__ int cur[TILE];
    const int b = blockIdx.x % HB;
    const int t = blockIdx.x / HB;
    const int lo = b * chunk;
    const int hi = min(lo + chunk, E);
    const int t0 = t * TILE;
    const int tl = min(TILE, N - t0);
    const bool f32 = flag[0] != 0;

    const unsigned short* base = cnt + (size_t)(t * HB + b) * TILE;
    for (int i = threadIdx.x; i < tl; i += 256)
        cur[i] = rowstart[t0 + i] + (int)base[i];
    __syncthreads();
    for (int e = lo + threadIdx.x; e < hi; e += 256) {
        const int s = src[e] - t0;
        if ((unsigned)s < (unsigned)tl) {
            const int pos = atomicAdd(&cur[s], 1);
            const float x = ldf(r_ij, 3 * e + 0, f32);
            const float y = ldf(r_ij, 3 * e + 1, f32);
            const float z = ldf(r_ij, 3 * e + 2, f32);
            const float d2 = x * x + y * y + z * z;
            const float inv = rsqrtf(1.0f + 49.0f * d2);  // tens_sigmoid(7r)
            const float u = fminf(sqrtf(d2), DMAX) * ((float)(TSIZE - 1) / DMAX);
            const int ti = (int)(u + 0.5f);               // nearest, <= TSIZE-1
            const float rs0 = 7.0f * x * inv, rs1 = 7.0f * y * inv,
                        rs2 = 7.0f * z * inv;
            if (P16) {
                ((float4*)epsv)[pos] =
                    make_float4(rs0, rs1, rs2, __int_as_float(ti * ROWB));
            } else {
                const unsigned int h0 = __half_as_ushort(__float2half(rs0));
                const unsigned int h1 = __half_as_ushort(__float2half(rs1));
                const unsigned int h2 = __half_as_ushort(__float2half(rs2));
                ((uint2*)epsv)[pos] =
                    make_uint2(h0 | (h1 << 16), h2 | ((unsigned)ti << 16));
            }
        }
    }
}

// --- per-node accumulation: TWO nodes per wave, asm-forced 8-wide loads ----
// lane = (half = lane>>5, channel a = lane&31); each lane owns all 13 outputs
// of channel a of node n0+half.  Per batch of 8 edges: asm block of 8
// payload dwordx4 + vmcnt(0), then asm block of 8 table dwordx4 + vmcnt(0)
// (aligned, 16-B quads), then 8 x 22 VALU.  ~2 latency events / 8 edges.
// Remainder: same shape, indices clamped to [0,mylen-1], zero-masked.
#define ACC16(Q, U)                                                           \
    do {                                                                      \
        const float x = (Q).x, y = (Q).y, z = (Q).z;                          \
        accA += (U).x;                                                        \
        v0 += (U).y * x; v1 += (U).y * y; v2 += (U).y * z;                    \
        const float _tx = (U).z * x, _ty = (U).z * y, _tz = (U).z * z;        \
        d00 += _tx * x; d01 += _tx * y; d02 += _tx * z;                       \
        d10 += _ty * x; d11 += _ty * y; d12 += _ty * z;                       \
        d20 += _tz * x; d21 += _tz * y; d22 += _tz * z;                       \
    } while (0)

template <bool P16>
__global__ void __launch_bounds__(64 * NPB, 4) k_nodes2(
    const void* __restrict__ epsv,
    const int* __restrict__ rowstart,
    const float* __restrict__ tabI,
    const int* __restrict__ flag,
    void* __restrict__ out, int N) {
    const int wave = threadIdx.x >> 6;
    const int lane = threadIdx.x & 63;
    const int n0 = (blockIdx.x * NPB + wave) * 2;
    const int a = lane & 31;
    const int half = lane >> 5;
    const int myn = n0 + half;
    const bool f32 = flag[0] != 0;
    const char* tabA = (const char*)tabI + a * 16;   // 16-B quad base

    int s0 = 0, s1 = 0;
    if (myn < N) { s0 = rowstart[myn]; s1 = rowstart[myn + 1]; }
    const int mylen = s1 - s0;
    const int lenA = __shfl(mylen, 0);
    const int lenB = __shfl(mylen, 32);
    const int minl = min(lenA, lenB);
    const int maxl = max(lenA, lenB);
    const int mclamp = max(mylen - 1, 0);

    float accA = 0.f, v0 = 0.f, v1 = 0.f, v2 = 0.f;
    float d00 = 0.f, d01 = 0.f, d02 = 0.f,
          d10 = 0.f, d11 = 0.f, d12 = 0.f,
          d20 = 0.f, d21 = 0.f, d22 = 0.f;

    if (P16) {
        int i = 0;
        // ---- main: unpredicated 8-wide batches up to minl ----
        for (; i + 8 <= minl; i += 8) {
            const char* pb = (const char*)epsv + (size_t)(s0 + i) * 16;
            f32x4 q0, q1, q2, q3, q4, q5, q6, q7;
            load8x16(pb, pb + 16, pb + 32, pb + 48,
                     pb + 64, pb + 80, pb + 96, pb + 112,
                     q0, q1, q2, q3, q4, q5, q6, q7);
            f32x4 u0, u1, u2, u3, u4, u5, u6, u7;
            load8x16(tabA + __float_as_int(q0.w), tabA + __float_as_int(q1.w),
                     tabA + __float_as_int(q2.w), tabA + __float_as_int(q3.w),
                     tabA + __float_as_int(q4.w), tabA + __float_as_int(q5.w),
                     tabA + __float_as_int(q6.w), tabA + __float_as_int(q7.w),
                     u0, u1, u2, u3, u4, u5, u6, u7);
            ACC16(q0, u0); ACC16(q1, u1); ACC16(q2, u2); ACC16(q3, u3);
            ACC16(q4, u4); ACC16(q5, u5); ACC16(q6, u6); ACC16(q7, u7);
        }
        // ---- remainder: predicated 8-wide batches up to maxl ----
        for (; i < maxl; i += 8) {
            float m0, m1, m2, m3, m4, m5, m6, m7;
#define TIDX(K) ((i + K) < mylen ? (i + K) : mclamp)
#define TPTR(K) ((const char*)epsv + (size_t)(s0 + TIDX(K)) * 16)
            m0 = (i + 0 < mylen) ? 1.f : 0.f;
            m1 = (i + 1 < mylen) ? 1.f : 0.f;
            m2 = (i + 2 < mylen) ? 1.f : 0.f;
            m3 = (i + 3 < mylen) ? 1.f : 0.f;
            m4 = (i + 4 < mylen) ? 1.f : 0.f;
            m5 = (i + 5 < mylen) ? 1.f : 0.f;
            m6 = (i + 6 < mylen) ? 1.f : 0.f;
            m7 = (i + 7 < mylen) ? 1.f : 0.f;
            f32x4 q0, q1, q2, q3, q4, q5, q6, q7;
            load8x16(TPTR(0), TPTR(1), TPTR(2), TPTR(3),
                     TPTR(4), TPTR(5), TPTR(6), TPTR(7),
                     q0, q1, q2, q3, q4, q5, q6, q7);
#undef TPTR
#undef TIDX
            f32x4 u0, u1, u2, u3, u4, u5, u6, u7;
            load8x16(tabA + __float_as_int(q0.w), tabA + __float_as_int(q1.w),
                     tabA + __float_as_int(q2.w), tabA + __float_as_int(q3.w),
                     tabA + __float_as_int(q4.w), tabA + __float_as_int(q5.w),
                     tabA + __float_as_int(q6.w), tabA + __float_as_int(q7.w),
                     u0, u1, u2, u3, u4, u5, u6, u7);
#define SAPX(K)                                                               \
            do { f32x4 uu = u##K; uu.x *= m##K; uu.y *= m##K; uu.z *= m##K;   \
                 ACC16(q##K, uu); } while (0)
            SAPX(0); SAPX(1); SAPX(2); SAPX(3);
            SAPX(4); SAPX(5); SAPX(6); SAPX(7);
#undef SAPX
        }
    } else {
        // ---- P8 fallback payload path (plain C, rarely used) ----
        for (int i = 0; i < maxl; i++) {
            if (i < mylen) {
                const u32x2 qh = *((const u32x2*)epsv + (s0 + i));
                const float x = __half2float(__ushort_as_half(
                    (unsigned short)(qh.x & 0xffffu)));
                const float y = __half2float(__ushort_as_half(
                    (unsigned short)(qh.x >> 16)));
                const float z = __half2float(__ushort_as_half(
                    (unsigned short)(qh.y & 0xffffu)));
                const TE t = *(const TE*)(tabA + (int)(qh.y >> 16) * ROWB);
                accA += t.r;
                v0 += t.v * x; v1 += t.v * y; v2 += t.v * z;
                const float _tx = t.d * x, _ty = t.d * y, _tz = t.d * z;
                d00 += _tx * x; d01 += _tx * y; d02 += _tx * z;
                d10 += _ty * x; d11 += _ty * y; d12 += _ty * z;
                d20 += _tz * x; d21 += _tz * y; d22 += _tz * z;
            }
        }
    }

    if (myn >= N) return;
    const size_t baseV = (size_t)N * 32;
    const size_t baseD = (size_t)N * 128;
    stf(out, (size_t)myn * 32 + a, accA, f32);
    const size_t vb = baseV + (size_t)myn * 96 + a * 3;
    stf(out, vb + 0, v0, f32);
    stf(out, vb + 1, v1, f32);
    stf(out, vb + 2, v2, f32);
    const size_t db = baseD + (size_t)myn * 288 + a * 9;
    stf(out, db + 0, d00, f32);
    stf(out, db + 1, d01, f32);
    stf(out, db + 2, d02, f32);
    stf(out, db + 3, d10, f32);
    stf(out, db + 4, d11, f32);
    stf(out, db + 5, d12, f32);
    stf(out, db + 6, d20, f32);
    stf(out, db + 7, d21, f32);
    stf(out, db + 8, d22, f32);
}

// --- fallback CSR (global atomics) + perm-based nodes ----------------------
__global__ void k_rank_g(const int* __restrict__ src, int* __restrict__ counts,
                         int* __restrict__ rank, int E) {
    int e = blockIdx.x * blockDim.x + threadIdx.x;
    if (e < E) rank[e] = atomicAdd(&counts[src[e]], 1);
}
__global__ void k_scan_g(const int* __restrict__ counts, int* __restrict__ rowstart,
                         int N, int E) {
    __shared__ int part[1024];
    const int t = threadIdx.x;
    const int CH = (N + 1023) / 1024;
    const int lo = t * CH;
    const int hi = min(lo + CH, N);
    int s = 0;
    for (int i = lo; i < hi; i++) s += counts[i];
    part[t] = s;
    __syncthreads();
    for (int off = 1; off < 1024; off <<= 1) {
        int v = part[t];
        int w = (t >= off) ? part[t - off] : 0;
        __syncthreads();
        part[t] = v + w;
        __syncthreads();
    }
    int run = (t == 0) ? 0 : part[t - 1];
    for (int i = lo; i < hi; i++) { rowstart[i] = run; run += counts[i]; }
    if (t == 0) rowstart[N] = E;
}
__global__ void k_place_g(const int* __restrict__ src, const int* __restrict__ rank,
                          const int* __restrict__ rowstart,
                          int* __restrict__ perm, int E) {
    int e = blockIdx.x * blockDim.x + threadIdx.x;
    if (e < E) perm[rowstart[src[e]] + rank[e]] = e;
}
__global__ void __launch_bounds__(256) k_nodes_fb(
    const int* __restrict__ perm, const void* __restrict__ r_ij,
    const int* __restrict__ rowstart, const float* __restrict__ tabI,
    const int* __restrict__ flag, void* __restrict__ out, int N) {
    const int wave = threadIdx.x >> 6;
    const int lane = threadIdx.x & 63;
    const int n = blockIdx.x * 4 + wave;
    if (n >= N) return;
    const int a = lane & 31;
    const bool hi = (lane >> 5) != 0;
    const bool f32 = flag[0] != 0;
    const int s0 = rowstart[n], s1 = rowstart[n + 1];
    float accR = 0.f, acc1 = 0.f, acc2 = 0.f, acc3 = 0.f,
          acc4 = 0.f, acc5 = 0.f, acc6 = 0.f;
    for (int idx = s0; idx < s1; idx++) {
        const int e = perm[idx];
        const float x0 = ldf(r_ij, 3 * e + 0, f32);
        const float y0 = ldf(r_ij, 3 * e + 1, f32);
        const float z0 = ldf(r_ij, 3 * e + 2, f32);
        const float d2 = x0 * x0 + y0 * y0 + z0 * z0;
        const float inv = rsqrtf(1.0f + 49.0f * d2);
        const float x = 7.0f * x0 * inv, y = 7.0f * y0 * inv, z = 7.0f * z0 * inv;
        const float u = fminf(sqrtf(d2), DMAX) * ((float)(TSIZE - 1) / DMAX);
        const int b = (int)(u + 0.5f) * ROWF + a * 4;   // padded row
        const float ra = tabI[b], rv = tabI[b + 1], rd = tabI[b + 2];
        const float b1 = (hi ? rd : rv) * (hi ? y : 1.0f);
        const float b2 = rd * (hi ? z : x);
        accR += ra;
        acc1 += b1 * x; acc2 += b1 * y; acc3 += b1 * z;
        acc4 += b2 * x; acc5 += b2 * y; acc6 += b2 * z;
    }
    const size_t baseV = (size_t)N * 32;
    const size_t baseD = (size_t)N * 128;
    if (!hi) {
        stf(out, (size_t)n * 32 + a, accR, f32);
        const size_t vb = baseV + (size_t)n * 96 + a * 3;
        stf(out, vb + 0, acc1, f32);
        stf(out, vb + 1, acc2, f32);
        stf(out, vb + 2, acc3, f32);
        const size_t db = baseD + (size_t)n * 288 + a * 9;
        stf(out, db + 0, acc4, f32);
        stf(out, db + 1, acc5, f32);
        stf(out, db + 2, acc6, f32);
    } else {
        const size_t db = baseD + (size_t)n * 288 + a * 9;
        stf(out, db + 3, acc1, f32);
        stf(out, db + 4, acc2, f32);
        stf(out, db + 5, acc3, f32);
        stf(out, db + 6, acc4, f32);
        stf(out, db + 7, acc5, f32);
        stf(out, db + 8, acc6, f32);
    }
}

extern "C" void kernel_launch(void* const* d_in, const int* in_sizes, int n_in,
                              void* d_out, int out_size, void* d_ws, size_t ws_size,
                              hipStream_t stream) {
    const void* r_ij     = d_in[0];
    const void* w_rad    = d_in[1];
    const void* b_rad    = d_in[2];
    const void* w_direct = d_in[3];
    const void* w1       = d_in[4];
    const void* b1       = d_in[5];
    const void* w2       = d_in[6];
    const void* b2       = d_in[7];
    const void* w3       = d_in[8];
    const void* b3       = d_in[9];
    const void* w_v      = d_in[10];
    const void* w_d      = d_in[11];
    const int* edges_src = (const int*)d_in[12];

    const int E = in_sizes[12];
    const int N = out_size / 416;   // 32 + 96 + 288 per node
    const int chunk = (E + HB - 1) / HB;
    const int ntiles = (N + TILE - 1) / TILE;
    const int NB = (N + 63) / 64;

    const size_t cntBytes  = (size_t)ntiles * HB * TILE * 2;
    const size_t tailBytes = ((size_t)W_TOT + 4) * 4 + (size_t)TSIZE * ROWF * 4
                           + cntBytes + ((size_t)N + NB + N + 1) * 4;
    const bool p16 = ws_size >= (size_t)E * 16 + tailBytes + 64;
    const bool p8  = !p16 && ws_size >= (size_t)E * 8 + tailBytes + 64;

    char* w = (char*)d_ws;
    if (p16 || p8) {
        const size_t slot = (size_t)E * (p16 ? 16 : 8);
        void* eps     = (void*)w;
        float* wcat   = (float*)(w + slot);
        int* flag     = (int*)(wcat + W_TOT);
        float* tabI   = (float*)(flag + 4);
        unsigned short* cnt = (unsigned short*)(tabI + (size_t)TSIZE * ROWF);
        int* tot      = (int*)((char*)cnt + cntBytes);
        int* coarse   = tot + N;              // NB entries
        int* rowstart = coarse + NB;          // N+1

        const int nodeBlocks = (N + 2 * NPB - 1) / (2 * NPB);
        k_prep<<<12, 256, 0, stream>>>(
            r_ij, w_rad, b_rad, w_direct, w1, b1, w2, b2, w3, b3, w_v, w_d,
            wcat, flag, nullptr, N);
        k_table<<<TSIZE / EPB, 64 * EPB, 0, stream>>>(wcat, tabI);
        k_hist<<<HB * ntiles, 256, 0, stream>>>(edges_src, E, chunk, cnt, N);
        k_colscan<<<NB, 64, 0, stream>>>(cnt, tot, coarse, N);
        k_scan2<<<NB, 64, 0, stream>>>(tot, coarse, rowstart, N);
        if (p16) {
            k_place<true><<<HB * ntiles, 256, 0, stream>>>(
                edges_src, E, chunk, cnt, rowstart, r_ij, flag, eps, N);
            k_nodes2<true><<<nodeBlocks, 64 * NPB, 0, stream>>>(
                eps, rowstart, tabI, flag, d_out, N);
        } else {
            k_place<false><<<HB * ntiles, 256, 0, stream>>>(
                edges_src, E, chunk, cnt, rowstart, r_ij, flag, eps, N);
            k_nodes2<false><<<nodeBlocks, 64 * NPB, 0, stream>>>(
                eps, rowstart, tabI, flag, d_out, N);
        }
    } else {
        // fallback: global-atomic rank path, perm-indexed nodes
        int* perm     = (int*)w;              // E
        float* wcat   = (float*)(w + (size_t)E * 4);
        int* flag     = (int*)(wcat + W_TOT);
        float* tabI   = (float*)(flag + 4);
        int* counts   = (int*)(tabI + (size_t)TSIZE * ROWF);
        int* rowstart = counts + N;           // N+1
        int* rank     = rowstart + N + 1;     // E

        k_prep<<<12 + (N + 255) / 256, 256, 0, stream>>>(
            r_ij, w_rad, b_rad, w_direct, w1, b1, w2, b2, w3, b3, w_v, w_d,
            wcat, flag, counts, N);
        k_table<<<TSIZE / EPB, 64 * EPB, 0, stream>>>(wcat, tabI);
        k_rank_g<<<(E + 255) / 256, 256, 0, stream>>>(edges_src, counts, rank, E);
        k_scan_g<<<1, 1024, 0, stream>>>(counts, rowstart, N, E);
        k_place_g<<<(E + 255) / 256, 256, 0, stream>>>(edges_src, rank, rowstart,
                                                       perm, E);
        k_nodes_fb<<<(N + 3) / 4, 256, 0, stream>>>(
            perm, r_ij, rowstart, tabI, flag, d_out, N);
    }
}